// Round 8
// baseline (2865.637 us; speedup 1.0000x reference)
//
#include <hip/hip_runtime.h>
#include <hip/hip_bf16.h>

#define D_DIM 3072
#define NTRAIN 16384
#define NTEST 8192

typedef __attribute__((ext_vector_type(8))) short short8;
typedef __attribute__((ext_vector_type(4))) float f32x4;

__device__ __forceinline__ unsigned short f2bf(float f) {
  union { float f; unsigned u; } x; x.f = f;
  unsigned r = x.u + 0x7FFFu + ((x.u >> 16) & 1u);
  return (unsigned short)(r >> 16);
}

__device__ __forceinline__ void gload16(const unsigned short* g, unsigned short* l) {
  __builtin_amdgcn_global_load_lds(
      (__attribute__((address_space(1))) void*)g,
      (__attribute__((address_space(3))) void*)l, 16, 0, 0);
}

// T1: bijective chunked XCD swizzle + 8x8 supertile ordering.
// Requires gx%8==0 and gy%8==0 (all grids below satisfy this).
__device__ __forceinline__ void swz_tile(int& tileY, int& tileX) {
  const int gx = gridDim.x, gy = gridDim.y;
  const int L = blockIdx.y * gx + blockIdx.x;
  const int q = (gx * gy) >> 3;
  const int s = (L & 7) * q + (L >> 3);   // chunked per-XCD
  const int sid = s >> 6;                 // supertile id (64 tiles)
  const int t = s & 63;
  const int scols = gx >> 3;
  const int sy = sid / scols, sx = sid - sy * scols;
  tileY = sy * 8 + (t >> 3);
  tileX = sx * 8 + (t & 7);
}

// ---------------- pass 0: converts / transpose / copy ----------------
__global__ void k_convert(const float* __restrict__ in, unsigned short* __restrict__ out, long n4) {
  long i = (long)blockIdx.x * blockDim.x + threadIdx.x;
  long stride = (long)gridDim.x * blockDim.x;
  for (; i < n4; i += stride) {
    float4 v = reinterpret_cast<const float4*>(in)[i];
    ushort4 o;
    o.x = f2bf(v.x); o.y = f2bf(v.y); o.z = f2bf(v.z); o.w = f2bf(v.w);
    reinterpret_cast<ushort4*>(out)[i] = o;
  }
}

__global__ void k_copy4(const float4* __restrict__ in, float4* __restrict__ out, long n4) {
  long i = (long)blockIdx.x * blockDim.x + threadIdx.x;
  long stride = (long)gridDim.x * blockDim.x;
  for (; i < n4; i += stride) out[i] = in[i];
}

// Mt[n][k] = bf16(M[k][n])
__global__ void k_transpose_bf16(const float* __restrict__ M, unsigned short* __restrict__ Mt) {
  __shared__ float t[32][33];
  int bx = blockIdx.x * 32, by = blockIdx.y * 32;
  int tx = threadIdx.x, ty = threadIdx.y;  // 32 x 8
#pragma unroll
  for (int i = 0; i < 32; i += 8)
    t[ty + i][tx] = M[(size_t)(by + ty + i) * D_DIM + bx + tx];
  __syncthreads();
#pragma unroll
  for (int i = 0; i < 32; i += 8)
    Mt[(size_t)(bx + ty + i) * D_DIM + by + tx] = f2bf(t[tx][ty + i]);
}

// ------- BT main loop, 512 threads (8 waves), 64x64 wave tiles, T2 swizzle -------
// Block tile = (WM*64) x (WN*64), WM*WN = 8. AR/BR = 64-row staging chunks.
// LDS read traffic: (64+64)*64*2B per wave-step for 64*64*64 MACs = 0.0625 B/MAC
// (m97 ratio; R5's 32x64 tile was 0.094 and LDS-BW-bound at 31% MfmaUtil).
template <int WM, int WN, int AR, int BR>
__device__ __forceinline__ void mainloopT(const unsigned short* __restrict__ A,
                                          const unsigned short* __restrict__ B,
                                          int K, int rowBase, int colBase,
                                          unsigned short* As, unsigned short* Bs,
                                          f32x4 acc[4][4]) {
  const int tid = threadIdx.x;
  const int lane = tid & 63;
  const int wave = tid >> 6;
  const int wm = wave / WN, wn = wave % WN;
  const int sr = tid >> 3;                       // staging row 0..63 (+c*64)
  const int ssl = tid & 7;                       // physical 16B slot
  const int scol = ((ssl ^ (sr & 7)) * 8);       // pre-swizzled global column
  const unsigned short* ga = A + (size_t)(rowBase + sr) * K + scol;
  const unsigned short* gb = B + (size_t)(colBase + sr) * K + scol;
  const int arow = wm * 64 + (lane & 15);
  const int brow = wn * 64 + (lane & 15);
  const int lsw = lane & 7;
  const int lhi = lane >> 4;
  for (int k0 = 0; k0 < K; k0 += 64) {
#pragma unroll
    for (int c = 0; c < AR; ++c)
      gload16(ga + (size_t)c * 64 * K + k0, As + c * 4096 + tid * 8);
#pragma unroll
    for (int c = 0; c < BR; ++c)
      gload16(gb + (size_t)c * 64 * K + k0, Bs + c * 4096 + tid * 8);
    __syncthreads();
#pragma unroll
    for (int kk = 0; kk < 2; ++kk) {
      short8 af[4], bfr[4];
      const int sl = ((lhi + kk * 4) ^ lsw) * 8;  // swizzled read slot
#pragma unroll
      for (int i = 0; i < 4; ++i)
        af[i] = *reinterpret_cast<const short8*>(&As[(arow + i * 16) * 64 + sl]);
#pragma unroll
      for (int j = 0; j < 4; ++j)
        bfr[j] = *reinterpret_cast<const short8*>(&Bs[(brow + j * 16) * 64 + sl]);
#pragma unroll
      for (int i = 0; i < 4; ++i)
#pragma unroll
        for (int j = 0; j < 4; ++j)
          acc[i][j] = __builtin_amdgcn_mfma_f32_16x16x32_bf16(af[i], bfr[j], acc[i][j], 0, 0, 0);
    }
    __syncthreads();
  }
}

// ---- GEMM1: X @ M (B = Mt). Block 256x128 (WM=4, WN=2). Epilogue: norm2 (+ sM) ----
template <bool WRITE_SM>
__global__ __launch_bounds__(512, 4) void k_gemm_xm(const unsigned short* __restrict__ A,
                                                    const unsigned short* __restrict__ Bt,
                                                    const float* __restrict__ Xf,
                                                    unsigned short* __restrict__ smOut,
                                                    float* __restrict__ norm) {
  __shared__ unsigned short As[4 * 4096], Bs[2 * 4096];  // 32 + 16 KiB
  int tileY, tileX;
  swz_tile(tileY, tileX);
  const int rowBase = tileY * 256, colBase = tileX * 128;
  f32x4 acc[4][4] = {};
  mainloopT<4, 2, 4, 2>(A, Bt, D_DIM, rowBase, colBase, As, Bs, acc);
  const int tid = threadIdx.x, lane = tid & 63;
  const int wave = tid >> 6;
  const int wm = wave >> 1, wn = wave & 1;
  const int r0 = wm * 64 + (lane >> 4) * 4;
  const int c0 = colBase + wn * 64 + (lane & 15);
#pragma unroll
  for (int mi = 0; mi < 4; ++mi) {
#pragma unroll
    for (int r = 0; r < 4; ++r) {
      const size_t grow = rowBase + r0 + mi * 16 + r;
      float v = 0.f;
#pragma unroll
      for (int ni = 0; ni < 4; ++ni) {
        float a = acc[mi][ni][r];
        int gcol = c0 + ni * 16;
        v += a * Xf[grow * D_DIM + gcol];
        if (WRITE_SM) smOut[grow * D_DIM + gcol] = f2bf(a);
      }
      v += __shfl_xor(v, 1); v += __shfl_xor(v, 2);
      v += __shfl_xor(v, 4); v += __shfl_xor(v, 8);
      if ((lane & 15) == 0) atomicAdd(&norm[grow], v);
    }
  }
}

// ---- GEMM2: sM @ x_test^T. Block 128x256 (WM=2, WN=4). Fused K + col partials ----
__global__ __launch_bounds__(512, 4) void k_gemm_cross(const unsigned short* __restrict__ sM,
                                                       const unsigned short* __restrict__ Xt16,
                                                       const float* __restrict__ Y,
                                                       const float* __restrict__ sn2,
                                                       const float* __restrict__ cn2,
                                                       float* __restrict__ part) {
  __shared__ unsigned short As[2 * 4096], Bs[4 * 4096];  // 16 + 32 KiB
  const int tid = threadIdx.x;
  int tileY, tileX;
  swz_tile(tileY, tileX);
  const int rowBase = tileY * 128, colBase = tileX * 256;
  f32x4 acc[4][4] = {};
  mainloopT<2, 4, 2, 4>(sM, Xt16, D_DIM, rowBase, colBase, As, Bs, acc);
  float* ylds = reinterpret_cast<float*>(As);                   // [128][12] padded
  float* snlds = ylds + 128 * 12;                               // [128]
  float (*pcol)[11] = reinterpret_cast<float(*)[11]>(Bs);       // [256][11]
  for (int i = tid; i < 1280; i += 512)
    ylds[(i / 10) * 12 + (i % 10)] = Y[(size_t)rowBase * 10 + i];
  if (tid < 128) snlds[tid] = sn2[rowBase + tid];
  for (int i = tid; i < 256 * 11; i += 512) (&pcol[0][0])[i] = 0.f;
  __syncthreads();
  const int lane = tid & 63;
  const int wave = tid >> 6;
  const int wm = wave >> 2, wn = wave & 3;
  const int r0 = wm * 64 + (lane >> 4) * 4;
  const int c0l = wn * 64 + (lane & 15);
#pragma unroll
  for (int ni = 0; ni < 4; ++ni) {
    const float cnv = cn2[colBase + c0l + ni * 16];
    float ps[11];
#pragma unroll
    for (int c = 0; c < 11; ++c) ps[c] = 0.f;
#pragma unroll
    for (int mi = 0; mi < 4; ++mi) {
#pragma unroll
      for (int r = 0; r < 4; ++r) {
        const int lrow = r0 + mi * 16 + r;
        float d2 = snlds[lrow] + cnv - 2.f * acc[mi][ni][r];
        float kv = exp2f(-0.14426950408889634f * sqrtf(fmaxf(d2, 0.f)));
        ps[10] += kv;
        f32x4 y0 = *reinterpret_cast<const f32x4*>(&ylds[lrow * 12]);
        f32x4 y1 = *reinterpret_cast<const f32x4*>(&ylds[lrow * 12 + 4]);
        float2 y2 = *reinterpret_cast<const float2*>(&ylds[lrow * 12 + 8]);
#pragma unroll
        for (int c = 0; c < 4; ++c) ps[c] += kv * y0[c];
#pragma unroll
        for (int c = 0; c < 4; ++c) ps[4 + c] += kv * y1[c];
        ps[8] += kv * y2.x;
        ps[9] += kv * y2.y;
      }
    }
#pragma unroll
    for (int c = 0; c < 11; ++c) {
      float v = ps[c];
      v += __shfl_xor(v, 16);
      v += __shfl_xor(v, 32);
      if (lane < 16) atomicAdd(&pcol[wn * 64 + ni * 16 + lane][c], v);
    }
  }
  __syncthreads();
  if (tid < 256) {
    int gcol = colBase + tid;
#pragma unroll
    for (int c = 0; c < 11; ++c)
      part[((size_t)tileY * 11 + c) * NTEST + gcol] = pcol[tid][c];
  }
}

// ---------------- final reduce: out[t,c] = num/den ----------------
__global__ void k_reduce(const float* __restrict__ part, float* __restrict__ out) {
  int t = blockIdx.x * blockDim.x + threadIdx.x;  // 8192 threads
  float num[10] = {0, 0, 0, 0, 0, 0, 0, 0, 0, 0};
  float den = 0.f;
  for (int it = 0; it < NTRAIN / 128; ++it) {
    const float* p = part + (size_t)it * 11 * NTEST + t;
#pragma unroll
    for (int c = 0; c < 10; ++c) num[c] += p[(size_t)c * NTEST];
    den += p[(size_t)10 * NTEST];
  }
  float inv = 1.f / den;
#pragma unroll
  for (int c = 0; c < 10; ++c) out[(size_t)t * 10 + c] = num[c] * inv;
}

extern "C" void kernel_launch(void* const* d_in, const int* in_sizes, int n_in,
                              void* d_out, int out_size, void* d_ws, size_t ws_size,
                              hipStream_t stream) {
  const float* x_train = (const float*)d_in[0];
  const float* y_train = (const float*)d_in[1];
  const float* x_test  = (const float*)d_in[2];
  const float* M       = (const float*)d_in[3];
  float* out = (float*)d_out;

  char* ws = (char*)d_ws;
  unsigned short* xtr16 = (unsigned short*)(ws + 0);          // 16384*3072*2 = 100663296
  unsigned short* xte16 = (unsigned short*)(ws + 100663296);  // 8192*3072*2  = 50331648
  unsigned short* Mt16  = (unsigned short*)(ws + 150994944);  // 3072*3072*2  = 18874368
  unsigned short* sM16  = (unsigned short*)(ws + 169869312);  // 16384*3072*2 = 100663296
  float* s_n2 = (float*)(ws + 270532608);                     // 65536
  float* c_n2 = (float*)(ws + 270598144);                     // 32768
  float* part = (float*)(ws + 270630912);                     // 128*11*8192*4 = 46137344

  hipMemsetAsync(ws + 270532608, 0, 98304, stream);  // s_n2 + c_n2

  k_convert<<<2048, 256, 0, stream>>>(x_train, xtr16, (long)NTRAIN * D_DIM / 4);
  k_convert<<<2048, 256, 0, stream>>>(x_test, xte16, (long)NTEST * D_DIM / 4);
  k_transpose_bf16<<<dim3(96, 96), dim3(32, 8), 0, stream>>>(M, Mt16);
  k_copy4<<<2048, 256, 0, stream>>>((const float4*)M, (float4*)(out + 81920),
                                    (long)D_DIM * D_DIM / 4);

  // xm: block 256 rows x 128 cols -> grid (3072/128, rows/256)
  k_gemm_xm<true><<<dim3(24, 64), 512, 0, stream>>>(xtr16, Mt16, x_train, sM16, s_n2);
  k_gemm_xm<false><<<dim3(24, 32), 512, 0, stream>>>(xte16, Mt16, x_test, nullptr, c_n2);

  // cross: block 128 rows x 256 cols -> grid (8192/256, 16384/128)
  k_gemm_cross<<<dim3(32, 128), 512, 0, stream>>>(sM16, xte16, y_train, s_n2, c_n2, part);
  k_reduce<<<32, 256, 0, stream>>>(part, out);
}

// Round 9
// 2655.950 us; speedup vs baseline: 1.0789x; 1.0789x over previous
//
#include <hip/hip_runtime.h>
#include <hip/hip_bf16.h>

#define D_DIM 3072
#define NTRAIN 16384
#define NTEST 8192

typedef __attribute__((ext_vector_type(8))) short short8;
typedef __attribute__((ext_vector_type(4))) float f32x4;

__device__ __forceinline__ unsigned short f2bf(float f) {
  union { float f; unsigned u; } x; x.f = f;
  unsigned r = x.u + 0x7FFFu + ((x.u >> 16) & 1u);
  return (unsigned short)(r >> 16);
}

__device__ __forceinline__ void gload16(const unsigned short* g, unsigned short* l) {
  __builtin_amdgcn_global_load_lds(
      (__attribute__((address_space(1))) void*)g,
      (__attribute__((address_space(3))) void*)l, 16, 0, 0);
}

// T1: bijective chunked XCD swizzle + 8x8 supertile ordering.
// Requires gx%8==0 and gy%8==0 (all GEMM grids below satisfy this).
__device__ __forceinline__ void swz_tile(int& tileY, int& tileX) {
  const int gx = gridDim.x, gy = gridDim.y;
  const int L = blockIdx.y * gx + blockIdx.x;
  const int q = (gx * gy) >> 3;
  const int s = (L & 7) * q + (L >> 3);   // chunked per-XCD
  const int sid = s >> 6;                 // supertile id (64 tiles)
  const int t = s & 63;
  const int scols = gx >> 3;
  const int sy = sid / scols, sx = sid - sy * scols;
  tileY = sy * 8 + (t >> 3);
  tileX = sx * 8 + (t & 7);
}

// ---------------- pass 0: converts / transpose / copy ----------------
__global__ void k_convert(const float* __restrict__ in, unsigned short* __restrict__ out, long n4) {
  long i = (long)blockIdx.x * blockDim.x + threadIdx.x;
  long stride = (long)gridDim.x * blockDim.x;
  for (; i < n4; i += stride) {
    float4 v = reinterpret_cast<const float4*>(in)[i];
    ushort4 o;
    o.x = f2bf(v.x); o.y = f2bf(v.y); o.z = f2bf(v.z); o.w = f2bf(v.w);
    reinterpret_cast<ushort4*>(out)[i] = o;
  }
}

__global__ void k_copy4(const float4* __restrict__ in, float4* __restrict__ out, long n4) {
  long i = (long)blockIdx.x * blockDim.x + threadIdx.x;
  long stride = (long)gridDim.x * blockDim.x;
  for (; i < n4; i += stride) out[i] = in[i];
}

// Mt[n][k] = bf16(M[k][n])
__global__ void k_transpose_bf16(const float* __restrict__ M, unsigned short* __restrict__ Mt) {
  __shared__ float t[32][33];
  int bx = blockIdx.x * 32, by = blockIdx.y * 32;
  int tx = threadIdx.x, ty = threadIdx.y;  // 32 x 8
#pragma unroll
  for (int i = 0; i < 32; i += 8)
    t[ty + i][tx] = M[(size_t)(by + ty + i) * D_DIM + bx + tx];
  __syncthreads();
#pragma unroll
  for (int i = 0; i < 32; i += 8)
    Mt[(size_t)(bx + ty + i) * D_DIM + by + tx] = f2bf(t[tx][ty + i]);
}

// ------- m97-shape 128x128 BT main loop: 256 threads, 4 waves (2Mx2N),
// 64x64 wave tiles (0.0625 B/MAC LDS ratio), T2 XOR-swizzle, K constexpr
// (strength-reduced addressing). UNCAPPED: target <=170 VGPR -> 3 waves/SIMD.
template <int K>
__device__ __forceinline__ void mainloop256(const unsigned short* __restrict__ A,
                                            const unsigned short* __restrict__ B,
                                            int rowBase, int colBase,
                                            unsigned short* As, unsigned short* Bs,
                                            f32x4 acc[4][4]) {
  const int tid = threadIdx.x;
  const int lane = tid & 63;
  const int wm = (tid >> 6) >> 1, wn = (tid >> 6) & 1;
  const int sr = tid >> 3;                       // staging row 0..31 (+c*32)
  const int ssl = tid & 7;                       // physical 16B slot
  const int scol = ((ssl ^ (sr & 7)) * 8);       // pre-swizzled global column
  const unsigned short* ga = A + (size_t)(rowBase + sr) * K + scol;
  const unsigned short* gb = B + (size_t)(colBase + sr) * K + scol;
  const int arow = wm * 64 + (lane & 15);
  const int brow = wn * 64 + (lane & 15);
  const int lsw = lane & 7;
  const int lhi = lane >> 4;
  for (int k0 = 0; k0 < K; k0 += 64) {
#pragma unroll
    for (int c = 0; c < 4; ++c) {
      gload16(ga + c * 32 * K + k0, As + c * 2048 + tid * 8);
      gload16(gb + c * 32 * K + k0, Bs + c * 2048 + tid * 8);
    }
    __syncthreads();
#pragma unroll
    for (int kk = 0; kk < 2; ++kk) {
      short8 af[4], bfr[4];
      const int sl = ((lhi + kk * 4) ^ lsw) * 8;  // swizzled read slot
#pragma unroll
      for (int i = 0; i < 4; ++i) {
        af[i]  = *reinterpret_cast<const short8*>(&As[(arow + i * 16) * 64 + sl]);
        bfr[i] = *reinterpret_cast<const short8*>(&Bs[(brow + i * 16) * 64 + sl]);
      }
#pragma unroll
      for (int i = 0; i < 4; ++i)
#pragma unroll
        for (int j = 0; j < 4; ++j)
          acc[i][j] = __builtin_amdgcn_mfma_f32_16x16x32_bf16(af[i], bfr[j], acc[i][j], 0, 0, 0);
    }
    __syncthreads();
  }
}

// ---- GEMM1: X @ M (B = Mt). 128x128 block. Epilogue: norm2 (+ optional sM) ----
template <bool WRITE_SM>
__global__ __launch_bounds__(256) void k_gemm_xm(const unsigned short* __restrict__ A,
                                                 const unsigned short* __restrict__ Bt,
                                                 const float* __restrict__ Xf,
                                                 unsigned short* __restrict__ smOut,
                                                 float* __restrict__ norm) {
  __shared__ unsigned short As[128 * 64], Bs[128 * 64];
  int tileY, tileX;
  swz_tile(tileY, tileX);
  const int rowBase = tileY * 128, colBase = tileX * 128;
  f32x4 acc[4][4] = {};
  mainloop256<D_DIM>(A, Bt, rowBase, colBase, As, Bs, acc);
  const int tid = threadIdx.x, lane = tid & 63;
  const int wm = (tid >> 6) >> 1, wn = (tid >> 6) & 1;
  const int r0 = wm * 64 + (lane >> 4) * 4;
  const int c0 = colBase + wn * 64 + (lane & 15);
#pragma unroll
  for (int mi = 0; mi < 4; ++mi) {
#pragma unroll
    for (int r = 0; r < 4; ++r) {
      const size_t grow = rowBase + r0 + mi * 16 + r;
      float v = 0.f;
#pragma unroll
      for (int ni = 0; ni < 4; ++ni) {
        float a = acc[mi][ni][r];
        int gcol = c0 + ni * 16;
        v += a * Xf[grow * D_DIM + gcol];
        if (WRITE_SM) smOut[grow * D_DIM + gcol] = f2bf(a);
      }
      v += __shfl_xor(v, 1); v += __shfl_xor(v, 2);
      v += __shfl_xor(v, 4); v += __shfl_xor(v, 8);
      if ((lane & 15) == 0) atomicAdd(&norm[grow], v);
    }
  }
}

// ---- GEMM2: sM @ x_test^T. 128x128 block. Light ni-outer fused epilogue ----
__global__ __launch_bounds__(256) void k_gemm_cross(const unsigned short* __restrict__ sM,
                                                    const unsigned short* __restrict__ Xt16,
                                                    const float* __restrict__ Y,
                                                    const float* __restrict__ sn2,
                                                    const float* __restrict__ cn2,
                                                    float* __restrict__ part) {
  __shared__ unsigned short As[128 * 64], Bs[128 * 64];
  const int tid = threadIdx.x;
  int tileY, tileX;
  swz_tile(tileY, tileX);
  const int rowBase = tileY * 128, colBase = tileX * 128;
  f32x4 acc[4][4] = {};
  mainloop256<D_DIM>(sM, Xt16, rowBase, colBase, As, Bs, acc);
  float* ylds = reinterpret_cast<float*>(As);                   // [128][12] padded
  float* snlds = ylds + 128 * 12;                               // [128]
  float (*pcol)[11] = reinterpret_cast<float(*)[11]>(Bs);       // [128][11]
  for (int i = tid; i < 1280; i += 256)
    ylds[(i / 10) * 12 + (i % 10)] = Y[(size_t)rowBase * 10 + i];
  if (tid < 128) snlds[tid] = sn2[rowBase + tid];
  for (int i = tid; i < 128 * 11; i += 256) (&pcol[0][0])[i] = 0.f;
  __syncthreads();
  const int lane = tid & 63;
  const int wm = (tid >> 6) >> 1, wn = (tid >> 6) & 1;
  const int r0 = wm * 64 + (lane >> 4) * 4;
  const int c0l = wn * 64 + (lane & 15);
#pragma unroll
  for (int ni = 0; ni < 4; ++ni) {
    const float cnv = cn2[colBase + c0l + ni * 16];
    float ps[11];
#pragma unroll
    for (int c = 0; c < 11; ++c) ps[c] = 0.f;
#pragma unroll
    for (int mi = 0; mi < 4; ++mi) {
#pragma unroll
      for (int r = 0; r < 4; ++r) {
        const int lrow = r0 + mi * 16 + r;
        float d2 = snlds[lrow] + cnv - 2.f * acc[mi][ni][r];
        float kv = exp2f(-0.14426950408889634f * sqrtf(fmaxf(d2, 0.f)));
        ps[10] += kv;
        f32x4 y0 = *reinterpret_cast<const f32x4*>(&ylds[lrow * 12]);
        f32x4 y1 = *reinterpret_cast<const f32x4*>(&ylds[lrow * 12 + 4]);
        float2 y2 = *reinterpret_cast<const float2*>(&ylds[lrow * 12 + 8]);
#pragma unroll
        for (int c = 0; c < 4; ++c) ps[c] += kv * y0[c];
#pragma unroll
        for (int c = 0; c < 4; ++c) ps[4 + c] += kv * y1[c];
        ps[8] += kv * y2.x;
        ps[9] += kv * y2.y;
      }
    }
#pragma unroll
    for (int c = 0; c < 11; ++c) {
      float v = ps[c];
      v += __shfl_xor(v, 16);
      v += __shfl_xor(v, 32);
      if (lane < 16) atomicAdd(&pcol[wn * 64 + ni * 16 + lane][c], v);
    }
  }
  __syncthreads();
  if (tid < 128) {
    int gcol = colBase + tid;
#pragma unroll
    for (int c = 0; c < 11; ++c)
      part[((size_t)tileY * 11 + c) * NTEST + gcol] = pcol[tid][c];
  }
}

// ---------------- final reduce: out[t,c] = num/den ----------------
__global__ void k_reduce(const float* __restrict__ part, float* __restrict__ out) {
  int t = blockIdx.x * blockDim.x + threadIdx.x;  // 8192 threads
  float num[10] = {0, 0, 0, 0, 0, 0, 0, 0, 0, 0};
  float den = 0.f;
  for (int it = 0; it < NTRAIN / 128; ++it) {
    const float* p = part + (size_t)it * 11 * NTEST + t;
#pragma unroll
    for (int c = 0; c < 10; ++c) num[c] += p[(size_t)c * NTEST];
    den += p[(size_t)10 * NTEST];
  }
  float inv = 1.f / den;
#pragma unroll
  for (int c = 0; c < 10; ++c) out[(size_t)t * 10 + c] = num[c] * inv;
}

extern "C" void kernel_launch(void* const* d_in, const int* in_sizes, int n_in,
                              void* d_out, int out_size, void* d_ws, size_t ws_size,
                              hipStream_t stream) {
  const float* x_train = (const float*)d_in[0];
  const float* y_train = (const float*)d_in[1];
  const float* x_test  = (const float*)d_in[2];
  const float* M       = (const float*)d_in[3];
  float* out = (float*)d_out;

  char* ws = (char*)d_ws;
  unsigned short* xtr16 = (unsigned short*)(ws + 0);          // 16384*3072*2 = 100663296
  unsigned short* xte16 = (unsigned short*)(ws + 100663296);  // 8192*3072*2  = 50331648
  unsigned short* Mt16  = (unsigned short*)(ws + 150994944);  // 3072*3072*2  = 18874368
  unsigned short* sM16  = (unsigned short*)(ws + 169869312);  // 16384*3072*2 = 100663296
  float* s_n2 = (float*)(ws + 270532608);                     // 65536
  float* c_n2 = (float*)(ws + 270598144);                     // 32768
  float* part = (float*)(ws + 270630912);                     // 128*11*8192*4 = 46137344

  hipMemsetAsync(ws + 270532608, 0, 98304, stream);  // s_n2 + c_n2

  k_convert<<<2048, 256, 0, stream>>>(x_train, xtr16, (long)NTRAIN * D_DIM / 4);
  k_convert<<<2048, 256, 0, stream>>>(x_test, xte16, (long)NTEST * D_DIM / 4);
  k_transpose_bf16<<<dim3(96, 96), dim3(32, 8), 0, stream>>>(M, Mt16);
  k_copy4<<<2048, 256, 0, stream>>>((const float4*)M, (float4*)(out + 81920),
                                    (long)D_DIM * D_DIM / 4);

  k_gemm_xm<true><<<dim3(24, 128), 256, 0, stream>>>(xtr16, Mt16, x_train, sM16, s_n2);
  k_gemm_xm<false><<<dim3(24, 64), 256, 0, stream>>>(xte16, Mt16, x_test, nullptr, c_n2);

  k_gemm_cross<<<dim3(64, 128), 256, 0, stream>>>(sM16, xte16, y_train, s_n2, c_n2, part);
  k_reduce<<<32, 256, 0, stream>>>(part, out);
}

// Round 10
// 2478.072 us; speedup vs baseline: 1.1564x; 1.0718x over previous
//
#include <hip/hip_runtime.h>
#include <hip/hip_bf16.h>

#define D_DIM 3072
#define NTRAIN 16384
#define NTEST 8192

typedef __attribute__((ext_vector_type(8))) short short8;
typedef __attribute__((ext_vector_type(4))) float f32x4;

__device__ __forceinline__ unsigned short f2bf(float f) {
  union { float f; unsigned u; } x; x.f = f;
  unsigned r = x.u + 0x7FFFu + ((x.u >> 16) & 1u);
  return (unsigned short)(r >> 16);
}

__device__ __forceinline__ void gload16(const unsigned short* g, unsigned short* l) {
  __builtin_amdgcn_global_load_lds(
      (__attribute__((address_space(1))) void*)g,
      (__attribute__((address_space(3))) void*)l, 16, 0, 0);
}

// T1: bijective chunked XCD swizzle + 8x8 supertile ordering (gx%8==0, gy%8==0).
__device__ __forceinline__ void swz_tile(int& tileY, int& tileX) {
  const int gx = gridDim.x, gy = gridDim.y;
  const int L = blockIdx.y * gx + blockIdx.x;
  const int q = (gx * gy) >> 3;
  const int s = (L & 7) * q + (L >> 3);
  const int sid = s >> 6;
  const int t = s & 63;
  const int scols = gx >> 3;
  const int sy = sid / scols, sx = sid - sy * scols;
  tileY = sy * 8 + (t >> 3);
  tileX = sx * 8 + (t & 7);
}

// ---------------- pass 0 ----------------
__global__ void k_convert(const float* __restrict__ in, unsigned short* __restrict__ out, long n4) {
  long i = (long)blockIdx.x * blockDim.x + threadIdx.x;
  long stride = (long)gridDim.x * blockDim.x;
  for (; i < n4; i += stride) {
    float4 v = reinterpret_cast<const float4*>(in)[i];
    ushort4 o;
    o.x = f2bf(v.x); o.y = f2bf(v.y); o.z = f2bf(v.z); o.w = f2bf(v.w);
    reinterpret_cast<ushort4*>(out)[i] = o;
  }
}

__global__ void k_copy4(const float4* __restrict__ in, float4* __restrict__ out, long n4) {
  long i = (long)blockIdx.x * blockDim.x + threadIdx.x;
  long stride = (long)gridDim.x * blockDim.x;
  for (; i < n4; i += stride) out[i] = in[i];
}

__global__ void k_transpose_bf16(const float* __restrict__ M, unsigned short* __restrict__ Mt) {
  __shared__ float t[32][33];
  int bx = blockIdx.x * 32, by = blockIdx.y * 32;
  int tx = threadIdx.x, ty = threadIdx.y;
#pragma unroll
  for (int i = 0; i < 32; i += 8)
    t[ty + i][tx] = M[(size_t)(by + ty + i) * D_DIM + bx + tx];
  __syncthreads();
#pragma unroll
  for (int i = 0; i < 32; i += 8)
    Mt[(size_t)(bx + ty + i) * D_DIM + by + tx] = f2bf(t[tx][ty + i]);
}

// ------- R6 xm main loop: 512 threads, 32x64 wave tiles, T2 swizzle (proven) -------
__device__ __forceinline__ void mainloopXM(const unsigned short* __restrict__ A,
                                           const unsigned short* __restrict__ B,
                                           int K, int rowBase, int colBase,
                                           unsigned short* As, unsigned short* Bs,
                                           f32x4 acc[2][4]) {
  const int tid = threadIdx.x;
  const int lane = tid & 63;
  const int wave = tid >> 6;
  const int wm = wave >> 1, wn = wave & 1;
  const int sr = tid >> 3;
  const int ssl = tid & 7;
  const int scol = ((ssl ^ (sr & 7)) * 8);
  const unsigned short* ga = A + (size_t)(rowBase + sr) * K + scol;
  const unsigned short* gb = B + (size_t)(colBase + sr) * K + scol;
  const int arow = wm * 32 + (lane & 15);
  const int brow = wn * 64 + (lane & 15);
  const int lsw = lane & 7;
  const int lhi = lane >> 4;
  for (int k0 = 0; k0 < K; k0 += 64) {
#pragma unroll
    for (int c = 0; c < 2; ++c) {
      gload16(ga + (size_t)c * 64 * K + k0, As + c * 4096 + tid * 8);
      gload16(gb + (size_t)c * 64 * K + k0, Bs + c * 4096 + tid * 8);
    }
    __syncthreads();
#pragma unroll
    for (int kk = 0; kk < 2; ++kk) {
      short8 af[2], bfr[4];
      const int sl = ((lhi + kk * 4) ^ lsw) * 8;
#pragma unroll
      for (int i = 0; i < 2; ++i)
        af[i] = *reinterpret_cast<const short8*>(&As[(arow + i * 16) * 64 + sl]);
#pragma unroll
      for (int j = 0; j < 4; ++j)
        bfr[j] = *reinterpret_cast<const short8*>(&Bs[(brow + j * 16) * 64 + sl]);
#pragma unroll
      for (int i = 0; i < 2; ++i)
#pragma unroll
        for (int j = 0; j < 4; ++j)
          acc[i][j] = __builtin_amdgcn_mfma_f32_16x16x32_bf16(af[i], bfr[j], acc[i][j], 0, 0, 0);
    }
    __syncthreads();
  }
}

// ---------------- GEMM1: X @ M (R6-exact structure) ----------------
template <bool WRITE_SM>
__global__ __launch_bounds__(512, 4) void k_gemm_xm(const unsigned short* __restrict__ A,
                                                    const unsigned short* __restrict__ Bt,
                                                    const float* __restrict__ Xf,
                                                    unsigned short* __restrict__ smOut,
                                                    float* __restrict__ norm) {
  __shared__ unsigned short As[128 * 64], Bs[128 * 64];
  int tileY, tileX;
  swz_tile(tileY, tileX);
  const int rowBase = tileY * 128, colBase = tileX * 128;
  f32x4 acc[2][4] = {};
  mainloopXM(A, Bt, D_DIM, rowBase, colBase, As, Bs, acc);
  const int tid = threadIdx.x, lane = tid & 63;
  const int wave = tid >> 6;
  const int wm = wave >> 1, wn = wave & 1;
  const int r0 = wm * 32 + (lane >> 4) * 4;
  const int c0 = colBase + wn * 64 + (lane & 15);
#pragma unroll
  for (int mi = 0; mi < 2; ++mi) {
#pragma unroll
    for (int r = 0; r < 4; ++r) {
      const size_t grow = rowBase + r0 + mi * 16 + r;
      float v = 0.f;
#pragma unroll
      for (int ni = 0; ni < 4; ++ni) {
        float a = acc[mi][ni][r];
        int gcol = c0 + ni * 16;
        v += a * Xf[grow * D_DIM + gcol];
        if (WRITE_SM) smOut[grow * D_DIM + gcol] = f2bf(a);
      }
      v += __shfl_xor(v, 1); v += __shfl_xor(v, 2);
      v += __shfl_xor(v, 4); v += __shfl_xor(v, 8);
      if ((lane & 15) == 0) atomicAdd(&norm[grow], v);
    }
  }
}

// ======== GEMM2: 256x256 tile, 8 waves, counted-vmcnt 4-phase schedule ========
// Stage unit = half-tile (128 rows x 64 cols = 2 gloads/thread). Issue order per
// K-tile t+1 (during tile t): [Bh0@ph0, Bh1@ph1, Ah0@ph2, Ah1@ph3].
// Phase (kk,mh) computes 16 MFMA. Needs: ph0:{Bh0,Bh1,Ah0}, ph1:+{Ah1}.
// Queue arithmetic (oldest-retire, 2 loads/half): steady waits = vmcnt(4)@ph0,
// vmcnt(4)@ph1 only; turnover barrier at ph3 end. Loads never drained to 0.
__device__ __forceinline__ void stage_half(const unsigned short* __restrict__ G,
                                           int base, int h, int k0,
                                           unsigned short* lds, int tid) {
#pragma unroll
  for (int j = 0; j < 2; ++j) {
    const int row = h * 128 + j * 64 + (tid >> 3);
    const int scol = ((tid & 7) ^ (row & 7)) * 8;    // pre-swizzled source (T2)
    gload16(G + (size_t)(base + row) * D_DIM + scol + k0,
            lds + h * 8192 + j * 4096 + tid * 8);
  }
}

__global__ __launch_bounds__(512, 2) void k_gemm_cross(const unsigned short* __restrict__ sM,
                                                       const unsigned short* __restrict__ Xt16,
                                                       const float* __restrict__ Y,
                                                       const float* __restrict__ sn2,
                                                       const float* __restrict__ cn2,
                                                       float* __restrict__ part) {
  __shared__ unsigned short As[2 * 16384], Bs[2 * 16384];  // 64 + 64 KiB
  const int tid = threadIdx.x, lane = tid & 63, wave = tid >> 6;
  const int wm = wave >> 2, wn = wave & 3;         // 2M x 4N
  const int l15 = lane & 15, lhi = lane >> 4;
  const int wmBase = wm * 64, wnBase = wn * 16;    // interleaved rep mapping
  int tileY, tileX;
  swz_tile(tileY, tileX);
  const int rowBase = tileY * 256, colBase = tileX * 256;
  f32x4 acc[8][4] = {};
  const int nt = D_DIM / 64;                       // 48

  // prologue: tile 0, halves in canonical order [B0,B1,A0,A1]
  stage_half(Xt16, colBase, 0, 0, Bs, tid);
  stage_half(Xt16, colBase, 1, 0, Bs, tid);
  stage_half(sM, rowBase, 0, 0, As, tid);
  stage_half(sM, rowBase, 1, 0, As, tid);

#define PHASE_COMPUTE(Ac, Bc, mh, kk, READB)                                       \
  {                                                                               \
    short8 af[4];                                                                 \
    const int ks = (kk) * 4 + lhi;                                                \
    _Pragma("unroll") for (int i = 0; i < 4; ++i) {                               \
      const int row = wmBase + (mh) * 128 + i * 16 + l15;                         \
      af[i] = *reinterpret_cast<const short8*>(&(Ac)[row * 64 + (((ks) ^ (row & 7)) * 8)]); \
    }                                                                             \
    if (READB) {                                                                  \
      _Pragma("unroll") for (int n = 0; n < 4; ++n) {                             \
        const int row = wnBase + n * 64 + l15;                                    \
        bfr[n] = *reinterpret_cast<const short8*>(&(Bc)[row * 64 + (((ks) ^ (row & 7)) * 8)]); \
      }                                                                           \
    }                                                                             \
    __builtin_amdgcn_s_setprio(1);                                                \
    _Pragma("unroll") for (int i = 0; i < 4; ++i)                                 \
      _Pragma("unroll") for (int n = 0; n < 4; ++n)                               \
        acc[(mh) * 4 + i][n] =                                                    \
            __builtin_amdgcn_mfma_f32_16x16x32_bf16(af[i], bfr[n], acc[(mh) * 4 + i][n], 0, 0, 0); \
    __builtin_amdgcn_s_setprio(0);                                                \
  }

  for (int t = 0; t < nt - 1; ++t) {
    const int p = t & 1;
    const unsigned short* Ac = As + p * 16384;
    const unsigned short* Bc = Bs + p * 16384;
    unsigned short* An = As + (p ^ 1) * 16384;
    unsigned short* Bn = Bs + (p ^ 1) * 16384;
    const int k1 = (t + 1) * 64;
    short8 bfr[4];
    // ph0
    stage_half(Xt16, colBase, 0, k1, Bn, tid);
    asm volatile("s_waitcnt vmcnt(4)" ::: "memory");
    __builtin_amdgcn_s_barrier();
    __builtin_amdgcn_sched_barrier(0);
    PHASE_COMPUTE(Ac, Bc, 0, 0, 1)
    // ph1
    stage_half(Xt16, colBase, 1, k1, Bn, tid);
    asm volatile("s_waitcnt vmcnt(4)" ::: "memory");
    __builtin_amdgcn_s_barrier();
    __builtin_amdgcn_sched_barrier(0);
    PHASE_COMPUTE(Ac, Bc, 1, 0, 0)
    // ph2
    stage_half(sM, rowBase, 0, k1, An, tid);
    PHASE_COMPUTE(Ac, Bc, 0, 1, 1)
    // ph3
    stage_half(sM, rowBase, 1, k1, An, tid);
    PHASE_COMPUTE(Ac, Bc, 1, 1, 0)
    __builtin_amdgcn_s_barrier();          // turnover fence
    __builtin_amdgcn_sched_barrier(0);
  }
  {  // peeled last tile (no staging)
    const int p = (nt - 1) & 1;
    const unsigned short* Ac = As + p * 16384;
    const unsigned short* Bc = Bs + p * 16384;
    short8 bfr[4];
    asm volatile("s_waitcnt vmcnt(2)" ::: "memory");
    __builtin_amdgcn_s_barrier();
    __builtin_amdgcn_sched_barrier(0);
    PHASE_COMPUTE(Ac, Bc, 0, 0, 1)
    asm volatile("s_waitcnt vmcnt(0)" ::: "memory");
    __builtin_amdgcn_s_barrier();
    __builtin_amdgcn_sched_barrier(0);
    PHASE_COMPUTE(Ac, Bc, 1, 0, 0)
    PHASE_COMPUTE(Ac, Bc, 0, 1, 1)
    PHASE_COMPUTE(Ac, Bc, 1, 1, 0)
  }
  __syncthreads();  // before LDS alias reuse

  // ---- fused epilogue: kv = exp2(-log2e/10 * sqrt(d2)); column partials ----
  float* ylds = reinterpret_cast<float*>(As);               // [256][12]
  float* snlds = ylds + 256 * 12;                           // [256]
  float (*pcol)[11] = reinterpret_cast<float(*)[11]>(Bs);   // [256][11]
  for (int i = tid; i < 2560; i += 512)
    ylds[(i / 10) * 12 + (i % 10)] = Y[(size_t)rowBase * 10 + i];
  if (tid < 256) snlds[tid] = sn2[rowBase + tid];
  for (int i = tid; i < 256 * 11; i += 512) (&pcol[0][0])[i] = 0.f;
  __syncthreads();
#pragma unroll
  for (int n = 0; n < 4; ++n) {
    const int clocal = wnBase + n * 64 + l15;
    const float cnv = cn2[colBase + clocal];
    float ps[11];
#pragma unroll
    for (int c = 0; c < 11; ++c) ps[c] = 0.f;
#pragma unroll
    for (int m = 0; m < 8; ++m) {
#pragma unroll
      for (int r = 0; r < 4; ++r) {
        const int lrow = wmBase + (m >> 2) * 128 + (m & 3) * 16 + lhi * 4 + r;
        float d2 = snlds[lrow] + cnv - 2.f * acc[m][n][r];
        float kv = exp2f(-0.14426950408889634f * sqrtf(fmaxf(d2, 0.f)));
        ps[10] += kv;
        f32x4 y0 = *reinterpret_cast<const f32x4*>(&ylds[lrow * 12]);
        f32x4 y1 = *reinterpret_cast<const f32x4*>(&ylds[lrow * 12 + 4]);
        float2 y2 = *reinterpret_cast<const float2*>(&ylds[lrow * 12 + 8]);
#pragma unroll
        for (int c = 0; c < 4; ++c) ps[c] += kv * y0[c];
#pragma unroll
        for (int c = 0; c < 4; ++c) ps[4 + c] += kv * y1[c];
        ps[8] += kv * y2.x;
        ps[9] += kv * y2.y;
      }
    }
#pragma unroll
    for (int c = 0; c < 11; ++c) {
      float v = ps[c];
      v += __shfl_xor(v, 16);
      v += __shfl_xor(v, 32);
      if (lane < 16) atomicAdd(&pcol[wnBase + n * 64 + lane][c], v);
    }
  }
  __syncthreads();
  if (tid < 256) {
    int gcol = colBase + tid;
#pragma unroll
    for (int c = 0; c < 11; ++c)
      part[((size_t)tileY * 11 + c) * NTEST + gcol] = pcol[tid][c];
  }
#undef PHASE_COMPUTE
}

// ---------------- final reduce ----------------
__global__ void k_reduce(const float* __restrict__ part, float* __restrict__ out) {
  int t = blockIdx.x * blockDim.x + threadIdx.x;
  float num[10] = {0, 0, 0, 0, 0, 0, 0, 0, 0, 0};
  float den = 0.f;
  for (int it = 0; it < NTRAIN / 256; ++it) {
    const float* p = part + (size_t)it * 11 * NTEST + t;
#pragma unroll
    for (int c = 0; c < 10; ++c) num[c] += p[(size_t)c * NTEST];
    den += p[(size_t)10 * NTEST];
  }
  float inv = 1.f / den;
#pragma unroll
  for (int c = 0; c < 10; ++c) out[(size_t)t * 10 + c] = num[c] * inv;
}

extern "C" void kernel_launch(void* const* d_in, const int* in_sizes, int n_in,
                              void* d_out, int out_size, void* d_ws, size_t ws_size,
                              hipStream_t stream) {
  const float* x_train = (const float*)d_in[0];
  const float* y_train = (const float*)d_in[1];
  const float* x_test  = (const float*)d_in[2];
  const float* M       = (const float*)d_in[3];
  float* out = (float*)d_out;

  char* ws = (char*)d_ws;
  unsigned short* xtr16 = (unsigned short*)(ws + 0);
  unsigned short* xte16 = (unsigned short*)(ws + 100663296);
  unsigned short* Mt16  = (unsigned short*)(ws + 150994944);
  unsigned short* sM16  = (unsigned short*)(ws + 169869312);
  float* s_n2 = (float*)(ws + 270532608);
  float* c_n2 = (float*)(ws + 270598144);
  float* part = (float*)(ws + 270630912);   // 64*11*8192*4 = 23068672

  hipMemsetAsync(ws + 270532608, 0, 98304, stream);

  k_convert<<<2048, 256, 0, stream>>>(x_train, xtr16, (long)NTRAIN * D_DIM / 4);
  k_convert<<<2048, 256, 0, stream>>>(x_test, xte16, (long)NTEST * D_DIM / 4);
  k_transpose_bf16<<<dim3(96, 96), dim3(32, 8), 0, stream>>>(M, Mt16);
  k_copy4<<<2048, 256, 0, stream>>>((const float4*)M, (float4*)(out + 81920),
                                    (long)D_DIM * D_DIM / 4);

  k_gemm_xm<true><<<dim3(24, 128), 512, 0, stream>>>(xtr16, Mt16, x_train, sM16, s_n2);
  k_gemm_xm<false><<<dim3(24, 64), 512, 0, stream>>>(xte16, Mt16, x_test, nullptr, c_n2);

  // cross: 256x256 tiles -> grid (8192/256, 16384/256)
  k_gemm_cross<<<dim3(32, 64), 512, 0, stream>>>(sM16, xte16, y_train, s_n2, c_n2, part);
  k_reduce<<<32, 256, 0, stream>>>(part, out);
}

// Round 11
// 1728.287 us; speedup vs baseline: 1.6581x; 1.4338x over previous
//
#include <hip/hip_runtime.h>
#include <hip/hip_bf16.h>

#define D_DIM 3072
#define NTRAIN 16384
#define NTEST 8192

typedef __attribute__((ext_vector_type(8))) short short8;
typedef __attribute__((ext_vector_type(4))) float f32x4;

__device__ __forceinline__ unsigned short f2bf(float f) {
  union { float f; unsigned u; } x; x.f = f;
  unsigned r = x.u + 0x7FFFu + ((x.u >> 16) & 1u);
  return (unsigned short)(r >> 16);
}

__device__ __forceinline__ void gload16(const void* g, void* l) {
  __builtin_amdgcn_global_load_lds(
      (const __attribute__((address_space(1))) void*)g,
      (__attribute__((address_space(3))) void*)l, 16, 0, 0);
}

// T1: bijective chunked XCD swizzle + 8x8 supertile ordering (gx%8==0, gy%8==0).
__device__ __forceinline__ void swz_tile(int& tileY, int& tileX) {
  const int gx = gridDim.x, gy = gridDim.y;
  const int L = blockIdx.y * gx + blockIdx.x;
  const int q = (gx * gy) >> 3;
  const int s = (L & 7) * q + (L >> 3);
  const int sid = s >> 6;
  const int t = s & 63;
  const int scols = gx >> 3;
  const int sy = sid / scols, sx = sid - sy * scols;
  tileY = sy * 8 + (t >> 3);
  tileX = sx * 8 + (t & 7);
}

// ---------------- pass 0 ----------------
__global__ void k_convert(const float* __restrict__ in, unsigned short* __restrict__ out, long n4) {
  long i = (long)blockIdx.x * blockDim.x + threadIdx.x;
  long stride = (long)gridDim.x * blockDim.x;
  for (; i < n4; i += stride) {
    float4 v = reinterpret_cast<const float4*>(in)[i];
    ushort4 o;
    o.x = f2bf(v.x); o.y = f2bf(v.y); o.z = f2bf(v.z); o.w = f2bf(v.w);
    reinterpret_cast<ushort4*>(out)[i] = o;
  }
}

// f32 -> fp8 e4m3 (OCP, saturating), 8 elems/thread-iter
__global__ void k_convert8(const float* __restrict__ in, unsigned char* __restrict__ out, long n8) {
  long i = (long)blockIdx.x * blockDim.x + threadIdx.x;
  long stride = (long)gridDim.x * blockDim.x;
  for (; i < n8; i += stride) {
    float4 a = reinterpret_cast<const float4*>(in)[i * 2];
    float4 b = reinterpret_cast<const float4*>(in)[i * 2 + 1];
    int w0 = __builtin_amdgcn_cvt_pk_fp8_f32(a.x, a.y, 0, false);
    w0 = __builtin_amdgcn_cvt_pk_fp8_f32(a.z, a.w, w0, true);
    int w1 = __builtin_amdgcn_cvt_pk_fp8_f32(b.x, b.y, 0, false);
    w1 = __builtin_amdgcn_cvt_pk_fp8_f32(b.z, b.w, w1, true);
    reinterpret_cast<int2*>(out)[i] = make_int2(w0, w1);
  }
}

__global__ void k_copy4(const float4* __restrict__ in, float4* __restrict__ out, long n4) {
  long i = (long)blockIdx.x * blockDim.x + threadIdx.x;
  long stride = (long)gridDim.x * blockDim.x;
  for (; i < n4; i += stride) out[i] = in[i];
}

__global__ void k_transpose_bf16(const float* __restrict__ M, unsigned short* __restrict__ Mt) {
  __shared__ float t[32][33];
  int bx = blockIdx.x * 32, by = blockIdx.y * 32;
  int tx = threadIdx.x, ty = threadIdx.y;
#pragma unroll
  for (int i = 0; i < 32; i += 8)
    t[ty + i][tx] = M[(size_t)(by + ty + i) * D_DIM + bx + tx];
  __syncthreads();
#pragma unroll
  for (int i = 0; i < 32; i += 8)
    Mt[(size_t)(bx + ty + i) * D_DIM + by + tx] = f2bf(t[tx][ty + i]);
}

// ------- R6 xm main loop: 512 threads, 32x64 wave tiles, bf16, T2 swizzle -------
__device__ __forceinline__ void mainloopXM(const unsigned short* __restrict__ A,
                                           const unsigned short* __restrict__ B,
                                           int K, int rowBase, int colBase,
                                           unsigned short* As, unsigned short* Bs,
                                           f32x4 acc[2][4]) {
  const int tid = threadIdx.x;
  const int lane = tid & 63;
  const int wave = tid >> 6;
  const int wm = wave >> 1, wn = wave & 1;
  const int sr = tid >> 3;
  const int ssl = tid & 7;
  const int scol = ((ssl ^ (sr & 7)) * 8);
  const unsigned short* ga = A + (size_t)(rowBase + sr) * K + scol;
  const unsigned short* gb = B + (size_t)(colBase + sr) * K + scol;
  const int arow = wm * 32 + (lane & 15);
  const int brow = wn * 64 + (lane & 15);
  const int lsw = lane & 7;
  const int lhi = lane >> 4;
  for (int k0 = 0; k0 < K; k0 += 64) {
#pragma unroll
    for (int c = 0; c < 2; ++c) {
      gload16(ga + (size_t)c * 64 * K + k0, As + c * 4096 + tid * 8);
      gload16(gb + (size_t)c * 64 * K + k0, Bs + c * 4096 + tid * 8);
    }
    __syncthreads();
#pragma unroll
    for (int kk = 0; kk < 2; ++kk) {
      short8 af[2], bfr[4];
      const int sl = ((lhi + kk * 4) ^ lsw) * 8;
#pragma unroll
      for (int i = 0; i < 2; ++i)
        af[i] = *reinterpret_cast<const short8*>(&As[(arow + i * 16) * 64 + sl]);
#pragma unroll
      for (int j = 0; j < 4; ++j)
        bfr[j] = *reinterpret_cast<const short8*>(&Bs[(brow + j * 16) * 64 + sl]);
#pragma unroll
      for (int i = 0; i < 2; ++i)
#pragma unroll
        for (int j = 0; j < 4; ++j)
          acc[i][j] = __builtin_amdgcn_mfma_f32_16x16x32_bf16(af[i], bfr[j], acc[i][j], 0, 0, 0);
    }
    __syncthreads();
  }
}

// ---- GEMM1: X @ M (R6-exact). Epilogue: norm2 (+ optional fp8 sM write) ----
template <bool WRITE_SM>
__global__ __launch_bounds__(512, 4) void k_gemm_xm(const unsigned short* __restrict__ A,
                                                    const unsigned short* __restrict__ Bt,
                                                    const float* __restrict__ Xf,
                                                    unsigned char* __restrict__ smOut,
                                                    float* __restrict__ norm) {
  __shared__ unsigned short As[128 * 64], Bs[128 * 64];
  int tileY, tileX;
  swz_tile(tileY, tileX);
  const int rowBase = tileY * 128, colBase = tileX * 128;
  f32x4 acc[2][4] = {};
  mainloopXM(A, Bt, D_DIM, rowBase, colBase, As, Bs, acc);
  const int tid = threadIdx.x, lane = tid & 63;
  const int wave = tid >> 6;
  const int wm = wave >> 1, wn = wave & 1;
  const int r0 = wm * 32 + (lane >> 4) * 4;
  const int c0 = colBase + wn * 64 + (lane & 15);
#pragma unroll
  for (int mi = 0; mi < 2; ++mi) {
#pragma unroll
    for (int r = 0; r < 4; ++r) {
      const size_t grow = rowBase + r0 + mi * 16 + r;
      float v = 0.f;
#pragma unroll
      for (int ni = 0; ni < 4; ++ni) {
        float a = acc[mi][ni][r];
        int gcol = c0 + ni * 16;
        v += a * Xf[grow * D_DIM + gcol];
        if (WRITE_SM) {
          int p = __builtin_amdgcn_cvt_pk_fp8_f32(a, a, 0, false);
          smOut[grow * D_DIM + gcol] = (unsigned char)(p & 0xFF);
        }
      }
      v += __shfl_xor(v, 1); v += __shfl_xor(v, 2);
      v += __shfl_xor(v, 4); v += __shfl_xor(v, 8);
      if ((lane & 15) == 0) atomicAdd(&norm[grow], v);
    }
  }
}

// ======== GEMM2: fp8 e4m3, 128x128 tile, 512 thr, 32x64 wave tiles ========
// LDS rows are 64 BYTES (BK=64 fp8). 16B-granule swizzle: phys16 = s ^ f(row),
// f(r) = (r ^ (r>>2)) & 3 (involution; <=2-way banks on ds_read_b64).
// Staging: 1 gload16 per matrix per thread per K-step (pre-swizzled source).
__global__ __launch_bounds__(512, 4) void k_gemm_cross(const unsigned char* __restrict__ sM8,
                                                       const unsigned char* __restrict__ xte8,
                                                       const float* __restrict__ Y,
                                                       const float* __restrict__ sn2,
                                                       const float* __restrict__ cn2,
                                                       float* __restrict__ part) {
  __shared__ unsigned char As[128 * 64], Bs[128 * 64];  // 8 + 8 KiB
  const int tid = threadIdx.x;
  int tileY, tileX;
  swz_tile(tileY, tileX);
  const int rowBase = tileY * 128, colBase = tileX * 128;
  const int lane = tid & 63;
  const int wave = tid >> 6;
  const int wm = wave >> 1, wn = wave & 1;   // 4M x 2N of 32x64
  const int l15 = lane & 15, lhi = lane >> 4;
  const int arow = wm * 32 + l15;
  const int brow = wn * 64 + l15;
  // staging addresses (pre-swizzled global source)
  const int srow = tid >> 2;                 // 0..127
  const int sslot = tid & 3;
  const int fsr = (srow ^ (srow >> 2)) & 3;
  const unsigned char* ga = sM8 + (size_t)(rowBase + srow) * D_DIM + ((sslot ^ fsr) * 16);
  const unsigned char* gb = xte8 + (size_t)(colBase + srow) * D_DIM + ((sslot ^ fsr) * 16);

  f32x4 acc[2][4] = {};
  for (int k0 = 0; k0 < D_DIM; k0 += 64) {
    gload16(ga + k0, As + tid * 16);
    gload16(gb + k0, Bs + tid * 16);
    __syncthreads();
#pragma unroll
    for (int kk = 0; kk < 2; ++kk) {
      long long af[2], bfr[4];
      const int ks = kk * 4 + lhi;           // 8B chunk index 0..7
#pragma unroll
      for (int i = 0; i < 2; ++i) {
        const int row = arow + i * 16;
        const int fr = (row ^ (row >> 2)) & 3;
        af[i] = *reinterpret_cast<const long long*>(
            &As[row * 64 + ((((ks >> 1) ^ fr) * 2 + (ks & 1)) * 8)]);
      }
#pragma unroll
      for (int j = 0; j < 4; ++j) {
        const int row = brow + j * 16;
        const int fr = (row ^ (row >> 2)) & 3;
        bfr[j] = *reinterpret_cast<const long long*>(
            &Bs[row * 64 + ((((ks >> 1) ^ fr) * 2 + (ks & 1)) * 8)]);
      }
#pragma unroll
      for (int i = 0; i < 2; ++i)
#pragma unroll
        for (int j = 0; j < 4; ++j)
          acc[i][j] = __builtin_amdgcn_mfma_f32_16x16x32_fp8_fp8(af[i], bfr[j], acc[i][j], 0, 0, 0);
    }
    __syncthreads();
  }

  // ---- fused epilogue (R6-exact): kv = exp2(-log2e/10*sqrt(d2)); col partials ----
  float* ylds = reinterpret_cast<float*>(As);                 // [128][12] padded (6KB)
  float* snlds = ylds + 128 * 12;                             // [128] -> 6.6KB <= 8KB
  float (*pcol)[11] = reinterpret_cast<float(*)[11]>(Bs);     // [128][11] (5.6KB)
  for (int i = tid; i < 1280; i += 512)
    ylds[(i / 10) * 12 + (i % 10)] = Y[(size_t)rowBase * 10 + i];
  if (tid < 128) snlds[tid] = sn2[rowBase + tid];
  for (int i = tid; i < 128 * 11; i += 512) (&pcol[0][0])[i] = 0.f;
  __syncthreads();
  const int r0 = wm * 32 + lhi * 4;
  const int c0l = wn * 64 + l15;
#pragma unroll
  for (int ni = 0; ni < 4; ++ni) {
    const float cnv = cn2[colBase + c0l + ni * 16];
    float ps[11];
#pragma unroll
    for (int c = 0; c < 11; ++c) ps[c] = 0.f;
#pragma unroll
    for (int mi = 0; mi < 2; ++mi) {
#pragma unroll
      for (int r = 0; r < 4; ++r) {
        const int lrow = r0 + mi * 16 + r;
        float d2 = snlds[lrow] + cnv - 2.f * acc[mi][ni][r];
        float kv = exp2f(-0.14426950408889634f * sqrtf(fmaxf(d2, 0.f)));
        ps[10] += kv;
        f32x4 y0 = *reinterpret_cast<const f32x4*>(&ylds[lrow * 12]);
        f32x4 y1 = *reinterpret_cast<const f32x4*>(&ylds[lrow * 12 + 4]);
        float2 y2 = *reinterpret_cast<const float2*>(&ylds[lrow * 12 + 8]);
#pragma unroll
        for (int c = 0; c < 4; ++c) ps[c] += kv * y0[c];
#pragma unroll
        for (int c = 0; c < 4; ++c) ps[4 + c] += kv * y1[c];
        ps[8] += kv * y2.x;
        ps[9] += kv * y2.y;
      }
    }
#pragma unroll
    for (int c = 0; c < 11; ++c) {
      float v = ps[c];
      v += __shfl_xor(v, 16);
      v += __shfl_xor(v, 32);
      if (lane < 16) atomicAdd(&pcol[wn * 64 + ni * 16 + lane][c], v);
    }
  }
  __syncthreads();
  if (tid < 128) {
    int gcol = colBase + tid;
#pragma unroll
    for (int c = 0; c < 11; ++c)
      part[((size_t)tileY * 11 + c) * NTEST + gcol] = pcol[tid][c];
  }
}

// ---------------- final reduce ----------------
__global__ void k_reduce(const float* __restrict__ part, float* __restrict__ out) {
  int t = blockIdx.x * blockDim.x + threadIdx.x;
  float num[10] = {0, 0, 0, 0, 0, 0, 0, 0, 0, 0};
  float den = 0.f;
  for (int it = 0; it < NTRAIN / 128; ++it) {
    const float* p = part + (size_t)it * 11 * NTEST + t;
#pragma unroll
    for (int c = 0; c < 10; ++c) num[c] += p[(size_t)c * NTEST];
    den += p[(size_t)10 * NTEST];
  }
  float inv = 1.f / den;
#pragma unroll
  for (int c = 0; c < 10; ++c) out[(size_t)t * 10 + c] = num[c] * inv;
}

extern "C" void kernel_launch(void* const* d_in, const int* in_sizes, int n_in,
                              void* d_out, int out_size, void* d_ws, size_t ws_size,
                              hipStream_t stream) {
  const float* x_train = (const float*)d_in[0];
  const float* y_train = (const float*)d_in[1];
  const float* x_test  = (const float*)d_in[2];
  const float* M       = (const float*)d_in[3];
  float* out = (float*)d_out;

  char* ws = (char*)d_ws;
  unsigned short* xtr16 = (unsigned short*)(ws + 0);          // 100663296
  unsigned short* xte16 = (unsigned short*)(ws + 100663296);  // 50331648
  unsigned short* Mt16  = (unsigned short*)(ws + 150994944);  // 18874368
  unsigned char*  sM8   = (unsigned char*)(ws + 169869312);   // 16384*3072 = 50331648
  unsigned char*  xte8  = (unsigned char*)(ws + 220200960);   // 8192*3072  = 25165824
  float* s_n2 = (float*)(ws + 245366784);                     // 65536
  float* c_n2 = (float*)(ws + 245432320);                     // 32768
  float* part = (float*)(ws + 245465088);                     // 128*11*8192*4 = 46137344

  hipMemsetAsync(ws + 245366784, 0, 98304, stream);  // s_n2 + c_n2

  k_convert<<<2048, 256, 0, stream>>>(x_train, xtr16, (long)NTRAIN * D_DIM / 4);
  k_convert<<<2048, 256, 0, stream>>>(x_test, xte16, (long)NTEST * D_DIM / 4);
  k_convert8<<<1024, 256, 0, stream>>>(x_test, xte8, (long)NTEST * D_DIM / 8);
  k_transpose_bf16<<<dim3(96, 96), dim3(32, 8), 0, stream>>>(M, Mt16);
  k_copy4<<<2048, 256, 0, stream>>>((const float4*)M, (float4*)(out + 81920),
                                    (long)D_DIM * D_DIM / 4);

  k_gemm_xm<true><<<dim3(24, 128), 512, 0, stream>>>(xtr16, Mt16, x_train, sM8, s_n2);
  k_gemm_xm<false><<<dim3(24, 64), 512, 0, stream>>>(xte16, Mt16, x_test, nullptr, c_n2);

  k_gemm_cross<<<dim3(64, 128), 512, 0, stream>>>(sM8, xte8, y_train, s_n2, c_n2, part);
  k_reduce<<<32, 256, 0, stream>>>(part, out);
}

// Round 12
// 1614.126 us; speedup vs baseline: 1.7753x; 1.0707x over previous
//
#include <hip/hip_runtime.h>
#include <hip/hip_bf16.h>

#define D_DIM 3072
#define NTRAIN 16384
#define NTEST 8192

typedef __attribute__((ext_vector_type(8))) short short8;
typedef __attribute__((ext_vector_type(4))) float f32x4;
typedef __attribute__((ext_vector_type(2))) long long ll2;

__device__ __forceinline__ unsigned short f2bf(float f) {
  union { float f; unsigned u; } x; x.f = f;
  unsigned r = x.u + 0x7FFFu + ((x.u >> 16) & 1u);
  return (unsigned short)(r >> 16);
}

__device__ __forceinline__ void gload16(const void* g, void* l) {
  __builtin_amdgcn_global_load_lds(
      (const __attribute__((address_space(1))) void*)g,
      (__attribute__((address_space(3))) void*)l, 16, 0, 0);
}

// T1: bijective chunked XCD swizzle + 8x8 supertile ordering (gx%8==0, gy%8==0).
__device__ __forceinline__ void swz_tile(int& tileY, int& tileX) {
  const int gx = gridDim.x, gy = gridDim.y;
  const int L = blockIdx.y * gx + blockIdx.x;
  const int q = (gx * gy) >> 3;
  const int s = (L & 7) * q + (L >> 3);
  const int sid = s >> 6;
  const int t = s & 63;
  const int scols = gx >> 3;
  const int sy = sid / scols, sx = sid - sy * scols;
  tileY = sy * 8 + (t >> 3);
  tileX = sx * 8 + (t & 7);
}

// ---------------- pass 0 ----------------
__global__ void k_convert(const float* __restrict__ in, unsigned short* __restrict__ out, long n4) {
  long i = (long)blockIdx.x * blockDim.x + threadIdx.x;
  long stride = (long)gridDim.x * blockDim.x;
  for (; i < n4; i += stride) {
    float4 v = reinterpret_cast<const float4*>(in)[i];
    ushort4 o;
    o.x = f2bf(v.x); o.y = f2bf(v.y); o.z = f2bf(v.z); o.w = f2bf(v.w);
    reinterpret_cast<ushort4*>(out)[i] = o;
  }
}

// f32 -> fp8 e4m3 (OCP, saturating), 8 elems/thread-iter
__global__ void k_convert8(const float* __restrict__ in, unsigned char* __restrict__ out, long n8) {
  long i = (long)blockIdx.x * blockDim.x + threadIdx.x;
  long stride = (long)gridDim.x * blockDim.x;
  for (; i < n8; i += stride) {
    float4 a = reinterpret_cast<const float4*>(in)[i * 2];
    float4 b = reinterpret_cast<const float4*>(in)[i * 2 + 1];
    int w0 = __builtin_amdgcn_cvt_pk_fp8_f32(a.x, a.y, 0, false);
    w0 = __builtin_amdgcn_cvt_pk_fp8_f32(a.z, a.w, w0, true);
    int w1 = __builtin_amdgcn_cvt_pk_fp8_f32(b.x, b.y, 0, false);
    w1 = __builtin_amdgcn_cvt_pk_fp8_f32(b.z, b.w, w1, true);
    reinterpret_cast<int2*>(out)[i] = make_int2(w0, w1);
  }
}

__global__ void k_copy4(const float4* __restrict__ in, float4* __restrict__ out, long n4) {
  long i = (long)blockIdx.x * blockDim.x + threadIdx.x;
  long stride = (long)gridDim.x * blockDim.x;
  for (; i < n4; i += stride) out[i] = in[i];
}

__global__ void k_transpose_bf16(const float* __restrict__ M, unsigned short* __restrict__ Mt) {
  __shared__ float t[32][33];
  int bx = blockIdx.x * 32, by = blockIdx.y * 32;
  int tx = threadIdx.x, ty = threadIdx.y;
#pragma unroll
  for (int i = 0; i < 32; i += 8)
    t[ty + i][tx] = M[(size_t)(by + ty + i) * D_DIM + bx + tx];
  __syncthreads();
#pragma unroll
  for (int i = 0; i < 32; i += 8)
    Mt[(size_t)(bx + ty + i) * D_DIM + by + tx] = f2bf(t[tx][ty + i]);
}

// ------- R6 xm main loop: 512 threads, 32x64 wave tiles, bf16, T2 swizzle -------
__device__ __forceinline__ void mainloopXM(const unsigned short* __restrict__ A,
                                           const unsigned short* __restrict__ B,
                                           int K, int rowBase, int colBase,
                                           unsigned short* As, unsigned short* Bs,
                                           f32x4 acc[2][4]) {
  const int tid = threadIdx.x;
  const int lane = tid & 63;
  const int wave = tid >> 6;
  const int wm = wave >> 1, wn = wave & 1;
  const int sr = tid >> 3;
  const int ssl = tid & 7;
  const int scol = ((ssl ^ (sr & 7)) * 8);
  const unsigned short* ga = A + (size_t)(rowBase + sr) * K + scol;
  const unsigned short* gb = B + (size_t)(colBase + sr) * K + scol;
  const int arow = wm * 32 + (lane & 15);
  const int brow = wn * 64 + (lane & 15);
  const int lsw = lane & 7;
  const int lhi = lane >> 4;
  for (int k0 = 0; k0 < K; k0 += 64) {
#pragma unroll
    for (int c = 0; c < 2; ++c) {
      gload16(ga + (size_t)c * 64 * K + k0, As + c * 4096 + tid * 8);
      gload16(gb + (size_t)c * 64 * K + k0, Bs + c * 4096 + tid * 8);
    }
    __syncthreads();
#pragma unroll
    for (int kk = 0; kk < 2; ++kk) {
      short8 af[2], bfr[4];
      const int sl = ((lhi + kk * 4) ^ lsw) * 8;
#pragma unroll
      for (int i = 0; i < 2; ++i)
        af[i] = *reinterpret_cast<const short8*>(&As[(arow + i * 16) * 64 + sl]);
#pragma unroll
      for (int j = 0; j < 4; ++j)
        bfr[j] = *reinterpret_cast<const short8*>(&Bs[(brow + j * 16) * 64 + sl]);
#pragma unroll
      for (int i = 0; i < 2; ++i)
#pragma unroll
        for (int j = 0; j < 4; ++j)
          acc[i][j] = __builtin_amdgcn_mfma_f32_16x16x32_bf16(af[i], bfr[j], acc[i][j], 0, 0, 0);
    }
    __syncthreads();
  }
}

// ---- GEMM1: X @ M (R6-exact). Epilogue: norm2 (+ optional fp8 sM write) ----
template <bool WRITE_SM>
__global__ __launch_bounds__(512, 4) void k_gemm_xm(const unsigned short* __restrict__ A,
                                                    const unsigned short* __restrict__ Bt,
                                                    const float* __restrict__ Xf,
                                                    unsigned char* __restrict__ smOut,
                                                    float* __restrict__ norm) {
  __shared__ unsigned short As[128 * 64], Bs[128 * 64];
  int tileY, tileX;
  swz_tile(tileY, tileX);
  const int rowBase = tileY * 128, colBase = tileX * 128;
  f32x4 acc[2][4] = {};
  mainloopXM(A, Bt, D_DIM, rowBase, colBase, As, Bs, acc);
  const int tid = threadIdx.x, lane = tid & 63;
  const int wave = tid >> 6;
  const int wm = wave >> 1, wn = wave & 1;
  const int r0 = wm * 32 + (lane >> 4) * 4;
  const int c0 = colBase + wn * 64 + (lane & 15);
#pragma unroll
  for (int mi = 0; mi < 2; ++mi) {
#pragma unroll
    for (int r = 0; r < 4; ++r) {
      const size_t grow = rowBase + r0 + mi * 16 + r;
      float v = 0.f;
#pragma unroll
      for (int ni = 0; ni < 4; ++ni) {
        float a = acc[mi][ni][r];
        int gcol = c0 + ni * 16;
        v += a * Xf[grow * D_DIM + gcol];
        if (WRITE_SM) {
          int p = __builtin_amdgcn_cvt_pk_fp8_f32(a, a, 0, false);
          smOut[grow * D_DIM + gcol] = (unsigned char)(p & 0xFF);
        }
      }
      v += __shfl_xor(v, 1); v += __shfl_xor(v, 2);
      v += __shfl_xor(v, 4); v += __shfl_xor(v, 8);
      if ((lane & 15) == 0) atomicAdd(&norm[grow], v);
    }
  }
}

// ======== GEMM2: fp8 e4m3, 128x128 tile, 512 thr, 32x64 wave tiles ========
// K-permutation trick: MFMA call (kk,lhi) consumes global 8B-chunk 2*lhi+kk
// (valid since A and B share the permutation). One ds_read_b128 at granule
// lhi^f(row) yields BOTH kk frags -> 6 b128 reads + 16 MFMA per K-step
// (72 vs 80 cycles, balanced). f(r) = (r^(r>>2))&3; 2 lanes/bank = free.
__global__ __launch_bounds__(512, 4) void k_gemm_cross(const unsigned char* __restrict__ sM8,
                                                       const unsigned char* __restrict__ xte8,
                                                       const float* __restrict__ Y,
                                                       const float* __restrict__ sn2,
                                                       const float* __restrict__ cn2,
                                                       float* __restrict__ part) {
  __shared__ unsigned char As[128 * 64], Bs[128 * 64];  // 8 + 8 KiB
  const int tid = threadIdx.x;
  int tileY, tileX;
  swz_tile(tileY, tileX);
  const int rowBase = tileY * 128, colBase = tileX * 128;
  const int lane = tid & 63;
  const int wave = tid >> 6;
  const int wm = wave >> 1, wn = wave & 1;   // 4M x 2N of 32x64
  const int l15 = lane & 15, lhi = lane >> 4;
  const int arow = wm * 32 + l15;
  const int brow = wn * 64 + l15;
  // staging addresses (pre-swizzled global source, 16B granule involution)
  const int srow = tid >> 2;                 // 0..127
  const int sslot = tid & 3;
  const int fsr = (srow ^ (srow >> 2)) & 3;
  const unsigned char* ga = sM8 + (size_t)(rowBase + srow) * D_DIM + ((sslot ^ fsr) * 16);
  const unsigned char* gb = xte8 + (size_t)(colBase + srow) * D_DIM + ((sslot ^ fsr) * 16);

  f32x4 acc[2][4] = {};
  for (int k0 = 0; k0 < D_DIM; k0 += 64) {
    gload16(ga + k0, As + tid * 16);
    gload16(gb + k0, Bs + tid * 16);
    __syncthreads();
    ll2 a16[2], b16[4];
#pragma unroll
    for (int i = 0; i < 2; ++i) {
      const int row = arow + i * 16;
      const int fr = (row ^ (row >> 2)) & 3;
      a16[i] = *reinterpret_cast<const ll2*>(&As[row * 64 + ((lhi ^ fr) * 16)]);
    }
#pragma unroll
    for (int j = 0; j < 4; ++j) {
      const int row = brow + j * 16;
      const int fr = (row ^ (row >> 2)) & 3;
      b16[j] = *reinterpret_cast<const ll2*>(&Bs[row * 64 + ((lhi ^ fr) * 16)]);
    }
#pragma unroll
    for (int kk = 0; kk < 2; ++kk)
#pragma unroll
      for (int i = 0; i < 2; ++i)
#pragma unroll
        for (int j = 0; j < 4; ++j)
          acc[i][j] = __builtin_amdgcn_mfma_f32_16x16x32_fp8_fp8(a16[i][kk], b16[j][kk],
                                                                 acc[i][j], 0, 0, 0);
    __syncthreads();
  }

  // ---- fused epilogue (R6-exact): kv = exp2(-log2e/10*sqrt(d2)); col partials ----
  float* ylds = reinterpret_cast<float*>(As);                 // [128][12] padded (6KB)
  float* snlds = ylds + 128 * 12;                             // [128] -> 6.6KB <= 8KB
  float (*pcol)[11] = reinterpret_cast<float(*)[11]>(Bs);     // [128][11] (5.6KB)
  for (int i = tid; i < 1280; i += 512)
    ylds[(i / 10) * 12 + (i % 10)] = Y[(size_t)rowBase * 10 + i];
  if (tid < 128) snlds[tid] = sn2[rowBase + tid];
  for (int i = tid; i < 128 * 11; i += 512) (&pcol[0][0])[i] = 0.f;
  __syncthreads();
  const int r0 = wm * 32 + lhi * 4;
  const int c0l = wn * 64 + l15;
#pragma unroll
  for (int ni = 0; ni < 4; ++ni) {
    const float cnv = cn2[colBase + c0l + ni * 16];
    float ps[11];
#pragma unroll
    for (int c = 0; c < 11; ++c) ps[c] = 0.f;
#pragma unroll
    for (int mi = 0; mi < 2; ++mi) {
#pragma unroll
      for (int r = 0; r < 4; ++r) {
        const int lrow = r0 + mi * 16 + r;
        float d2 = snlds[lrow] + cnv - 2.f * acc[mi][ni][r];
        float kv = exp2f(-0.14426950408889634f * sqrtf(fmaxf(d2, 0.f)));
        ps[10] += kv;
        f32x4 y0 = *reinterpret_cast<const f32x4*>(&ylds[lrow * 12]);
        f32x4 y1 = *reinterpret_cast<const f32x4*>(&ylds[lrow * 12 + 4]);
        float2 y2 = *reinterpret_cast<const float2*>(&ylds[lrow * 12 + 8]);
#pragma unroll
        for (int c = 0; c < 4; ++c) ps[c] += kv * y0[c];
#pragma unroll
        for (int c = 0; c < 4; ++c) ps[4 + c] += kv * y1[c];
        ps[8] += kv * y2.x;
        ps[9] += kv * y2.y;
      }
    }
#pragma unroll
    for (int c = 0; c < 11; ++c) {
      float v = ps[c];
      v += __shfl_xor(v, 16);
      v += __shfl_xor(v, 32);
      if (lane < 16) atomicAdd(&pcol[wn * 64 + ni * 16 + lane][c], v);
    }
  }
  __syncthreads();
  if (tid < 128) {
    int gcol = colBase + tid;
#pragma unroll
    for (int c = 0; c < 11; ++c)
      part[((size_t)tileY * 11 + c) * NTEST + gcol] = pcol[tid][c];
  }
}

// ---------------- final reduce ----------------
__global__ void k_reduce(const float* __restrict__ part, float* __restrict__ out) {
  int t = blockIdx.x * blockDim.x + threadIdx.x;
  float num[10] = {0, 0, 0, 0, 0, 0, 0, 0, 0, 0};
  float den = 0.f;
  for (int it = 0; it < NTRAIN / 128; ++it) {
    const float* p = part + (size_t)it * 11 * NTEST + t;
#pragma unroll
    for (int c = 0; c < 10; ++c) num[c] += p[(size_t)c * NTEST];
    den += p[(size_t)10 * NTEST];
  }
  float inv = 1.f / den;
#pragma unroll
  for (int c = 0; c < 10; ++c) out[(size_t)t * 10 + c] = num[c] * inv;
}

extern "C" void kernel_launch(void* const* d_in, const int* in_sizes, int n_in,
                              void* d_out, int out_size, void* d_ws, size_t ws_size,
                              hipStream_t stream) {
  const float* x_train = (const float*)d_in[0];
  const float* y_train = (const float*)d_in[1];
  const float* x_test  = (const float*)d_in[2];
  const float* M       = (const float*)d_in[3];
  float* out = (float*)d_out;

  char* ws = (char*)d_ws;
  unsigned short* xtr16 = (unsigned short*)(ws + 0);          // 100663296
  unsigned short* xte16 = (unsigned short*)(ws + 100663296);  // 50331648
  unsigned short* Mt16  = (unsigned short*)(ws + 150994944);  // 18874368
  unsigned char*  sM8   = (unsigned char*)(ws + 169869312);   // 16384*3072 = 50331648
  unsigned char*  xte8  = (unsigned char*)(ws + 220200960);   // 8192*3072  = 25165824
  float* s_n2 = (float*)(ws + 245366784);                     // 65536
  float* c_n2 = (float*)(ws + 245432320);                     // 32768
  float* part = (float*)(ws + 245465088);                     // 128*11*8192*4 = 46137344

  hipMemsetAsync(ws + 245366784, 0, 98304, stream);  // s_n2 + c_n2

  k_convert<<<2048, 256, 0, stream>>>(x_train, xtr16, (long)NTRAIN * D_DIM / 4);
  k_convert<<<2048, 256, 0, stream>>>(x_test, xte16, (long)NTEST * D_DIM / 4);
  k_convert8<<<1024, 256, 0, stream>>>(x_test, xte8, (long)NTEST * D_DIM / 8);
  k_transpose_bf16<<<dim3(96, 96), dim3(32, 8), 0, stream>>>(M, Mt16);
  k_copy4<<<2048, 256, 0, stream>>>((const float4*)M, (float4*)(out + 81920),
                                    (long)D_DIM * D_DIM / 4);

  k_gemm_xm<true><<<dim3(24, 128), 512, 0, stream>>>(xtr16, Mt16, x_train, sM8, s_n2);
  k_gemm_xm<false><<<dim3(24, 64), 512, 0, stream>>>(xte16, Mt16, x_test, nullptr, c_n2);

  k_gemm_cross<<<dim3(64, 128), 512, 0, stream>>>(sM8, xte8, y_train, s_n2, c_n2, part);
  k_reduce<<<32, 256, 0, stream>>>(part, out);
}

// Round 13
// 1497.838 us; speedup vs baseline: 1.9132x; 1.0776x over previous
//
#include <hip/hip_runtime.h>
#include <hip/hip_bf16.h>

#define D_DIM 3072
#define NTRAIN 16384
#define NTEST 8192

typedef __attribute__((ext_vector_type(8))) short short8;
typedef __attribute__((ext_vector_type(4))) float f32x4;
typedef __attribute__((ext_vector_type(2))) long long ll2;

__device__ __forceinline__ unsigned short f2bf(float f) {
  union { float f; unsigned u; } x; x.f = f;
  unsigned r = x.u + 0x7FFFu + ((x.u >> 16) & 1u);
  return (unsigned short)(r >> 16);
}

__device__ __forceinline__ void gload16(const void* g, void* l) {
  __builtin_amdgcn_global_load_lds(
      (const __attribute__((address_space(1))) void*)g,
      (__attribute__((address_space(3))) void*)l, 16, 0, 0);
}

// T1: bijective chunked XCD swizzle + 8x8 supertile ordering (gx%8==0, gy%8==0).
__device__ __forceinline__ void swz_tile(int& tileY, int& tileX) {
  const int gx = gridDim.x, gy = gridDim.y;
  const int L = blockIdx.y * gx + blockIdx.x;
  const int q = (gx * gy) >> 3;
  const int s = (L & 7) * q + (L >> 3);
  const int sid = s >> 6;
  const int t = s & 63;
  const int scols = gx >> 3;
  const int sy = sid / scols, sx = sid - sy * scols;
  tileY = sy * 8 + (t >> 3);
  tileX = sx * 8 + (t & 7);
}

// ---------------- pass 0 ----------------
__global__ void k_convert(const float* __restrict__ in, unsigned short* __restrict__ out, long n4) {
  long i = (long)blockIdx.x * blockDim.x + threadIdx.x;
  long stride = (long)gridDim.x * blockDim.x;
  for (; i < n4; i += stride) {
    float4 v = reinterpret_cast<const float4*>(in)[i];
    ushort4 o;
    o.x = f2bf(v.x); o.y = f2bf(v.y); o.z = f2bf(v.z); o.w = f2bf(v.w);
    reinterpret_cast<ushort4*>(out)[i] = o;
  }
}

// f32 -> fp8 e4m3 (OCP, saturating), 8 elems/thread-iter
__global__ void k_convert8(const float* __restrict__ in, unsigned char* __restrict__ out, long n8) {
  long i = (long)blockIdx.x * blockDim.x + threadIdx.x;
  long stride = (long)gridDim.x * blockDim.x;
  for (; i < n8; i += stride) {
    float4 a = reinterpret_cast<const float4*>(in)[i * 2];
    float4 b = reinterpret_cast<const float4*>(in)[i * 2 + 1];
    int w0 = __builtin_amdgcn_cvt_pk_fp8_f32(a.x, a.y, 0, false);
    w0 = __builtin_amdgcn_cvt_pk_fp8_f32(a.z, a.w, w0, true);
    int w1 = __builtin_amdgcn_cvt_pk_fp8_f32(b.x, b.y, 0, false);
    w1 = __builtin_amdgcn_cvt_pk_fp8_f32(b.z, b.w, w1, true);
    reinterpret_cast<int2*>(out)[i] = make_int2(w0, w1);
  }
}

__global__ void k_copy4(const float4* __restrict__ in, float4* __restrict__ out, long n4) {
  long i = (long)blockIdx.x * blockDim.x + threadIdx.x;
  long stride = (long)gridDim.x * blockDim.x;
  for (; i < n4; i += stride) out[i] = in[i];
}

__global__ void k_transpose_bf16(const float* __restrict__ M, unsigned short* __restrict__ Mt) {
  __shared__ float t[32][33];
  int bx = blockIdx.x * 32, by = blockIdx.y * 32;
  int tx = threadIdx.x, ty = threadIdx.y;
#pragma unroll
  for (int i = 0; i < 32; i += 8)
    t[ty + i][tx] = M[(size_t)(by + ty + i) * D_DIM + bx + tx];
  __syncthreads();
#pragma unroll
  for (int i = 0; i < 32; i += 8)
    Mt[(size_t)(bx + ty + i) * D_DIM + by + tx] = f2bf(t[tx][ty + i]);
}

// ------- R6 xm main loop: 512 threads, 32x64 wave tiles, bf16, T2 swizzle -------
__device__ __forceinline__ void mainloopXM(const unsigned short* __restrict__ A,
                                           const unsigned short* __restrict__ B,
                                           int K, int rowBase, int colBase,
                                           unsigned short* As, unsigned short* Bs,
                                           f32x4 acc[2][4]) {
  const int tid = threadIdx.x;
  const int lane = tid & 63;
  const int wave = tid >> 6;
  const int wm = wave >> 1, wn = wave & 1;
  const int sr = tid >> 3;
  const int ssl = tid & 7;
  const int scol = ((ssl ^ (sr & 7)) * 8);
  const unsigned short* ga = A + (size_t)(rowBase + sr) * K + scol;
  const unsigned short* gb = B + (size_t)(colBase + sr) * K + scol;
  const int arow = wm * 32 + (lane & 15);
  const int brow = wn * 64 + (lane & 15);
  const int lsw = lane & 7;
  const int lhi = lane >> 4;
  for (int k0 = 0; k0 < K; k0 += 64) {
#pragma unroll
    for (int c = 0; c < 2; ++c) {
      gload16(ga + (size_t)c * 64 * K + k0, As + c * 4096 + tid * 8);
      gload16(gb + (size_t)c * 64 * K + k0, Bs + c * 4096 + tid * 8);
    }
    __syncthreads();
#pragma unroll
    for (int kk = 0; kk < 2; ++kk) {
      short8 af[2], bfr[4];
      const int sl = ((lhi + kk * 4) ^ lsw) * 8;
#pragma unroll
      for (int i = 0; i < 2; ++i)
        af[i] = *reinterpret_cast<const short8*>(&As[(arow + i * 16) * 64 + sl]);
#pragma unroll
      for (int j = 0; j < 4; ++j)
        bfr[j] = *reinterpret_cast<const short8*>(&Bs[(brow + j * 16) * 64 + sl]);
#pragma unroll
      for (int i = 0; i < 2; ++i)
#pragma unroll
        for (int j = 0; j < 4; ++j)
          acc[i][j] = __builtin_amdgcn_mfma_f32_16x16x32_bf16(af[i], bfr[j], acc[i][j], 0, 0, 0);
    }
    __syncthreads();
  }
}

// ---- GEMM1: X @ M (R6-exact). Epilogue: norm2 (+ optional fp8 sM write) ----
template <bool WRITE_SM>
__global__ __launch_bounds__(512, 4) void k_gemm_xm(const unsigned short* __restrict__ A,
                                                    const unsigned short* __restrict__ Bt,
                                                    const float* __restrict__ Xf,
                                                    unsigned char* __restrict__ smOut,
                                                    float* __restrict__ norm) {
  __shared__ unsigned short As[128 * 64], Bs[128 * 64];
  int tileY, tileX;
  swz_tile(tileY, tileX);
  const int rowBase = tileY * 128, colBase = tileX * 128;
  f32x4 acc[2][4] = {};
  mainloopXM(A, Bt, D_DIM, rowBase, colBase, As, Bs, acc);
  const int tid = threadIdx.x, lane = tid & 63;
  const int wave = tid >> 6;
  const int wm = wave >> 1, wn = wave & 1;
  const int r0 = wm * 32 + (lane >> 4) * 4;
  const int c0 = colBase + wn * 64 + (lane & 15);
#pragma unroll
  for (int mi = 0; mi < 2; ++mi) {
#pragma unroll
    for (int r = 0; r < 4; ++r) {
      const size_t grow = rowBase + r0 + mi * 16 + r;
      float v = 0.f;
#pragma unroll
      for (int ni = 0; ni < 4; ++ni) {
        float a = acc[mi][ni][r];
        int gcol = c0 + ni * 16;
        v += a * Xf[grow * D_DIM + gcol];
        if (WRITE_SM) {
          int p = __builtin_amdgcn_cvt_pk_fp8_f32(a, a, 0, false);
          smOut[grow * D_DIM + gcol] = (unsigned char)(p & 0xFF);
        }
      }
      v += __shfl_xor(v, 1); v += __shfl_xor(v, 2);
      v += __shfl_xor(v, 4); v += __shfl_xor(v, 8);
      if ((lane & 15) == 0) atomicAdd(&norm[grow], v);
    }
  }
}

// ======== GEMM2: fp8 e4m3, 128x128 tile, BK=128 (128-BYTE LDS rows) ========
// LDS row = 128 fp8 = 128 B = 8 slots of 16B; phys slot = l ^ (row&7) — the
// R2/R6 pattern measured at 0 bank conflicts. One b128 read (logical slot
// l = kp*4+lhi) yields TWO 8B MFMA operands (kk=0,1). K-permutation across
// (kp,lhi,kk) is legal: A and B share the mapping. Per K-128 iter:
// 4 gloads + 12 b128 (144 cy) + 32 MFMA (160 cy) -> MFMA-bound.
__global__ __launch_bounds__(512, 4) void k_gemm_cross(const unsigned char* __restrict__ sM8,
                                                       const unsigned char* __restrict__ xte8,
                                                       const float* __restrict__ Y,
                                                       const float* __restrict__ sn2,
                                                       const float* __restrict__ cn2,
                                                       float* __restrict__ part) {
  __shared__ unsigned char As[128 * 128], Bs[128 * 128];  // 16 + 16 KiB
  const int tid = threadIdx.x;
  int tileY, tileX;
  swz_tile(tileY, tileX);
  const int rowBase = tileY * 128, colBase = tileX * 128;
  const int lane = tid & 63;
  const int wave = tid >> 6;
  const int wm = wave >> 1, wn = wave & 1;   // 4M x 2N of 32x64
  const int l15 = lane & 15, lhi = lane >> 4;
  const int arow = wm * 32 + l15;
  const int brow = wn * 64 + l15;
  // staging: row = c*64 + (tid>>3), phys slot = tid&7, source chunk = slot^(row&7)
  const int srow = tid >> 3;                 // 0..63
  const int ssl = tid & 7;
  const unsigned char* ga = sM8 + (size_t)(rowBase + srow) * D_DIM + ((ssl ^ (srow & 7)) * 16);
  const unsigned char* gb = xte8 + (size_t)(colBase + srow) * D_DIM + ((ssl ^ (srow & 7)) * 16);

  f32x4 acc[2][4] = {};
  for (int k0 = 0; k0 < D_DIM; k0 += 128) {
#pragma unroll
    for (int c = 0; c < 2; ++c) {
      gload16(ga + (size_t)c * 64 * D_DIM + k0, As + c * 8192 + tid * 16);
      gload16(gb + (size_t)c * 64 * D_DIM + k0, Bs + c * 8192 + tid * 16);
    }
    __syncthreads();
#pragma unroll
    for (int kp = 0; kp < 2; ++kp) {
      ll2 a16[2], b16[4];
      const int l = kp * 4 + lhi;
#pragma unroll
      for (int i = 0; i < 2; ++i) {
        const int row = arow + i * 16;
        a16[i] = *reinterpret_cast<const ll2*>(&As[row * 128 + ((l ^ (row & 7)) * 16)]);
      }
#pragma unroll
      for (int j = 0; j < 4; ++j) {
        const int row = brow + j * 16;
        b16[j] = *reinterpret_cast<const ll2*>(&Bs[row * 128 + ((l ^ (row & 7)) * 16)]);
      }
#pragma unroll
      for (int kk = 0; kk < 2; ++kk)
#pragma unroll
        for (int i = 0; i < 2; ++i)
#pragma unroll
          for (int j = 0; j < 4; ++j)
            acc[i][j] = __builtin_amdgcn_mfma_f32_16x16x32_fp8_fp8(a16[i][kk], b16[j][kk],
                                                                   acc[i][j], 0, 0, 0);
    }
    __syncthreads();
  }

  // ---- fused epilogue (R6-exact): kv = exp2(-log2e/10*sqrt(d2)); col partials ----
  float* ylds = reinterpret_cast<float*>(As);                 // [128][12] padded
  float* snlds = ylds + 128 * 12;                             // [128]
  float (*pcol)[11] = reinterpret_cast<float(*)[11]>(Bs);     // [128][11]
  for (int i = tid; i < 1280; i += 512)
    ylds[(i / 10) * 12 + (i % 10)] = Y[(size_t)rowBase * 10 + i];
  if (tid < 128) snlds[tid] = sn2[rowBase + tid];
  for (int i = tid; i < 128 * 11; i += 512) (&pcol[0][0])[i] = 0.f;
  __syncthreads();
  const int r0 = wm * 32 + lhi * 4;
  const int c0l = wn * 64 + l15;
#pragma unroll
  for (int ni = 0; ni < 4; ++ni) {
    const float cnv = cn2[colBase + c0l + ni * 16];
    float ps[11];
#pragma unroll
    for (int c = 0; c < 11; ++c) ps[c] = 0.f;
#pragma unroll
    for (int mi = 0; mi < 2; ++mi) {
#pragma unroll
      for (int r = 0; r < 4; ++r) {
        const int lrow = r0 + mi * 16 + r;
        float d2 = snlds[lrow] + cnv - 2.f * acc[mi][ni][r];
        float kv = exp2f(-0.14426950408889634f * sqrtf(fmaxf(d2, 0.f)));
        ps[10] += kv;
        f32x4 y0 = *reinterpret_cast<const f32x4*>(&ylds[lrow * 12]);
        f32x4 y1 = *reinterpret_cast<const f32x4*>(&ylds[lrow * 12 + 4]);
        float2 y2 = *reinterpret_cast<const float2*>(&ylds[lrow * 12 + 8]);
#pragma unroll
        for (int c = 0; c < 4; ++c) ps[c] += kv * y0[c];
#pragma unroll
        for (int c = 0; c < 4; ++c) ps[4 + c] += kv * y1[c];
        ps[8] += kv * y2.x;
        ps[9] += kv * y2.y;
      }
    }
#pragma unroll
    for (int c = 0; c < 11; ++c) {
      float v = ps[c];
      v += __shfl_xor(v, 16);
      v += __shfl_xor(v, 32);
      if (lane < 16) atomicAdd(&pcol[wn * 64 + ni * 16 + lane][c], v);
    }
  }
  __syncthreads();
  if (tid < 128) {
    int gcol = colBase + tid;
#pragma unroll
    for (int c = 0; c < 11; ++c)
      part[((size_t)tileY * 11 + c) * NTEST + gcol] = pcol[tid][c];
  }
}

// ---------------- final reduce ----------------
__global__ void k_reduce(const float* __restrict__ part, float* __restrict__ out) {
  int t = blockIdx.x * blockDim.x + threadIdx.x;
  float num[10] = {0, 0, 0, 0, 0, 0, 0, 0, 0, 0};
  float den = 0.f;
  for (int it = 0; it < NTRAIN / 128; ++it) {
    const float* p = part + (size_t)it * 11 * NTEST + t;
#pragma unroll
    for (int c = 0; c < 10; ++c) num[c] += p[(size_t)c * NTEST];
    den += p[(size_t)10 * NTEST];
  }
  float inv = 1.f / den;
#pragma unroll
  for (int c = 0; c < 10; ++c) out[(size_t)t * 10 + c] = num[c] * inv;
}

extern "C" void kernel_launch(void* const* d_in, const int* in_sizes, int n_in,
                              void* d_out, int out_size, void* d_ws, size_t ws_size,
                              hipStream_t stream) {
  const float* x_train = (const float*)d_in[0];
  const float* y_train = (const float*)d_in[1];
  const float* x_test  = (const float*)d_in[2];
  const float* M       = (const float*)d_in[3];
  float* out = (float*)d_out;

  char* ws = (char*)d_ws;
  unsigned short* xtr16 = (unsigned short*)(ws + 0);          // 100663296
  unsigned short* xte16 = (unsigned short*)(ws + 100663296);  // 50331648
  unsigned short* Mt16  = (unsigned short*)(ws + 150994944);  // 18874368
  unsigned char*  sM8   = (unsigned char*)(ws + 169869312);   // 16384*3072 = 50331648
  unsigned char*  xte8  = (unsigned char*)(ws + 220200960);   // 8192*3072  = 25165824
  float* s_n2 = (float*)(ws + 245366784);                     // 65536
  float* c_n2 = (float*)(ws + 245432320);                     // 32768
  float* part = (float*)(ws + 245465088);                     // 128*11*8192*4 = 46137344

  hipMemsetAsync(ws + 245366784, 0, 98304, stream);  // s_n2 + c_n2

  k_convert<<<2048, 256, 0, stream>>>(x_train, xtr16, (long)NTRAIN * D_DIM / 4);
  k_convert<<<2048, 256, 0, stream>>>(x_test, xte16, (long)NTEST * D_DIM / 4);
  k_convert8<<<1024, 256, 0, stream>>>(x_test, xte8, (long)NTEST * D_DIM / 8);
  k_transpose_bf16<<<dim3(96, 96), dim3(32, 8), 0, stream>>>(M, Mt16);
  k_copy4<<<2048, 256, 0, stream>>>((const float4*)M, (float4*)(out + 81920),
                                    (long)D_DIM * D_DIM / 4);

  k_gemm_xm<true><<<dim3(24, 128), 512, 0, stream>>>(xtr16, Mt16, x_train, sM8, s_n2);
  k_gemm_xm<false><<<dim3(24, 64), 512, 0, stream>>>(xte16, Mt16, x_test, nullptr, c_n2);

  k_gemm_cross<<<dim3(64, 128), 512, 0, stream>>>(sM8, xte8, y_train, s_n2, c_n2, part);
  k_reduce<<<32, 256, 0, stream>>>(part, out);
}